// Round 1
// 379.244 us; speedup vs baseline: 1.1971x; 1.1971x over previous
//
#include <hip/hip_runtime.h>

#define BN_EPS 1e-5f
#define CHUNK 4096
#define MAXB 512  // max buckets (N up to 131072 with 256 nodes/bucket)

typedef __attribute__((ext_vector_type(8))) short short8v;  // 8 bf16 = 4 VGPRs
typedef __attribute__((ext_vector_type(4))) float f32x4;

// bf16 helpers (RNE pack, cheap unpack)
__device__ __forceinline__ unsigned short f2bf(float f) {
    unsigned int u = __float_as_uint(f);
    u += 0x7FFF + ((u >> 16) & 1);
    return (unsigned short)(u >> 16);
}
__device__ __forceinline__ float bf2f(unsigned short h) {
    return __uint_as_float((unsigned int)h << 16);
}

__device__ __forceinline__ short8v pack8(const float* f) {
    short8v r;
#pragma unroll
    for (int i = 0; i < 8; i++) r[i] = (short)f2bf(f[i]);
    return r;
}

// ---------------- CSR build: bucketed, no global random scatter ----------------

__global__ __launch_bounds__(256) void bin_count(const int* __restrict__ ei, int E,
                                                 int* __restrict__ bcnt, int nbuck) {
    __shared__ int h[MAXB];
    for (int i = threadIdx.x; i < nbuck; i += 256) h[i] = 0;
    __syncthreads();
    int i = blockIdx.x * 256 + threadIdx.x, stride = gridDim.x * 256;
    for (int e = i; e < E; e += stride) {
        int d = ei[E + e];
        atomicAdd(&h[d >> 8], 1);
    }
    __syncthreads();
    for (int b = threadIdx.x; b < nbuck; b += 256)
        if (h[b]) atomicAdd(&bcnt[b], h[b]);
}

__global__ __launch_bounds__(512) void scan_small(const int* __restrict__ bcnt,
                                                  int* __restrict__ boff,
                                                  int* __restrict__ bpos,
                                                  int* __restrict__ row_ptr_end,
                                                  int nbuck, int E) {
    __shared__ int wsum[8];
    int tid = threadIdx.x, lane = tid & 63, wv = tid >> 6;
    int val = (tid < nbuck) ? bcnt[tid] : 0;
    int s = val;
#pragma unroll
    for (int off = 1; off < 64; off <<= 1) {
        int t = __shfl_up(s, off, 64);
        if (lane >= off) s += t;
    }
    if (lane == 63) wsum[wv] = s;
    __syncthreads();
    if (wv == 0) {
        int t = (lane < 8) ? wsum[lane] : 0;
#pragma unroll
        for (int off = 1; off < 8; off <<= 1) {
            int u = __shfl_up(t, off, 64);
            if (lane >= off) t += u;
        }
        if (lane < 8) wsum[lane] = t;
    }
    __syncthreads();
    int excl = ((wv == 0) ? 0 : wsum[wv - 1]) + s - val;
    if (tid < nbuck) { boff[tid] = excl; bpos[tid] = excl; }
    if (tid == 0) { boff[nbuck] = E; *row_ptr_end = E; }
}

__global__ __launch_bounds__(256) void bin_scatter(const int* __restrict__ ei, int E,
                                                   int* __restrict__ bpos,
                                                   int* __restrict__ binned, int nbuck) {
    __shared__ int h[MAXB];
    __shared__ int res[MAXB];
    int base = blockIdx.x * CHUNK;
    int cnt = min(CHUNK, E - base);
    int tid = threadIdx.x;
    for (int b = tid; b < nbuck; b += 256) h[b] = 0;
    __syncthreads();
    for (int k = tid; k < cnt; k += 256) {
        int d = ei[E + base + k];
        atomicAdd(&h[d >> 8], 1);
    }
    __syncthreads();
    for (int b = tid; b < nbuck; b += 256) {
        int c = h[b];
        res[b] = c ? atomicAdd(&bpos[b], c) : 0;
        h[b] = 0;  // reuse as rank counter
    }
    __syncthreads();
    for (int k = tid; k < cnt; k += 256) {
        int srcv = ei[base + k];
        int d = ei[E + base + k];
        int b = d >> 8;
        int r = atomicAdd(&h[b], 1);
        binned[res[b] + r] = ((d & 255) << 17) | srcv;  // src < 2^17
    }
}

__global__ __launch_bounds__(256) void bucket_csr(const int* __restrict__ binned,
                                                  const int* __restrict__ boff,
                                                  int* __restrict__ row_ptr,
                                                  int* __restrict__ esrc, int N) {
    __shared__ int ncnt[256];
    __shared__ int npos[256];
    __shared__ int wsum[4];
    int b = blockIdx.x, tid = threadIdx.x, lane = tid & 63, wv = tid >> 6;
    int lo = boff[b], hi = boff[b + 1];
    int base_node = b << 8;
    ncnt[tid] = 0;
    __syncthreads();
    for (int i = lo + tid; i < hi; i += 256)
        atomicAdd(&ncnt[binned[i] >> 17], 1);
    __syncthreads();
    int c = ncnt[tid];
    int s = c;
#pragma unroll
    for (int off = 1; off < 64; off <<= 1) {
        int t = __shfl_up(s, off, 64);
        if (lane >= off) s += t;
    }
    if (lane == 63) wsum[wv] = s;
    __syncthreads();
    int woff = 0;
#pragma unroll
    for (int i = 0; i < 4; i++) woff += (i < wv) ? wsum[i] : 0;
    int abspos = lo + woff + (s - c);
    if (base_node + tid < N) row_ptr[base_node + tid] = abspos;
    npos[tid] = abspos;
    __syncthreads();
    for (int i = lo + tid; i < hi; i += 256) {
        int val = binned[i];
        int r = atomicAdd(&npos[val >> 17], 1);
        esrc[r] = val & 0x1FFFF;
    }
}

// ---------------- MFMA dense kernels ----------------
// Layout facts (gfx950 mfma_f32_16x16x32_bf16):
//   A frag: lane holds A[lane&15][(lane>>4)*8 + j], j=0..7 (short8v)
//   B frag: lane holds B[(lane>>4)*8 + j][lane&15]  (here = W[col][k] rows)
//   D frag: lane&15 = col, row = (lane>>4)*4 + reg  [verified layout per guide]
// LDS A-tile: 16 rows x (K/8) 16B slots, slot XOR-swizzled by row -> 2-way (free)

// Y[n][64](bf16) = X[n][128](f32) @ W[64][128]^T   (no bias; added in gather)
__global__ __launch_bounds__(256) void linear_mfma(const float* __restrict__ X,
                                                   const float* __restrict__ W,
                                                   unsigned short* __restrict__ Y, int N) {
    __shared__ short8v al[16 * 16];  // 16 rows x 16 slots (K=128)
    int tid = threadIdx.x, wv = tid >> 6, lane = tid & 63;
    int lr = lane & 15, lh = lane >> 4;
    // preload B frags: wave wv owns output cols [wv*16, wv*16+16)
    short8v bw[4];
    {
        const float* wrow = W + (size_t)(wv * 16 + lr) * 128;
#pragma unroll
        for (int kk = 0; kk < 4; kk++) {
            float tmp[8];
            *(float4*)tmp = *(const float4*)(wrow + kk * 32 + lh * 8);
            *(float4*)(tmp + 4) = *(const float4*)(wrow + kk * 32 + lh * 8 + 4);
            bw[kk] = pack8(tmp);
        }
    }
    int r = tid >> 4, s = tid & 15;  // staging: thread -> (row, slot)
    for (int nb = blockIdx.x * 16; nb < N; nb += gridDim.x * 16) {
        const float* xg = X + (size_t)(nb + r) * 128 + s * 8;
        float tmp[8];
        *(float4*)tmp = *(const float4*)xg;
        *(float4*)(tmp + 4) = *(const float4*)(xg + 4);
        al[r * 16 + (s ^ r)] = pack8(tmp);
        __syncthreads();
        f32x4 acc = {0.f, 0.f, 0.f, 0.f};
#pragma unroll
        for (int kk = 0; kk < 4; kk++) {
            short8v a = al[lr * 16 + ((kk * 4 + lh) ^ lr)];
            acc = __builtin_amdgcn_mfma_f32_16x16x32_bf16(a, bw[kk], acc, 0, 0, 0);
        }
        unsigned short* yb = Y + (size_t)nb * 64 + wv * 16 + lr;
#pragma unroll
        for (int ri = 0; ri < 4; ri++)
            yb[(size_t)(lh * 4 + ri) * 64] = f2bf(acc[ri]);
        __syncthreads();
    }
}

// H(bf16) = relu(bn(T@W^T + b))   (T bf16, K=64)
__global__ __launch_bounds__(256) void mlp1_mfma(const unsigned short* __restrict__ T,
        const float* __restrict__ W, const float* __restrict__ b,
        const float* __restrict__ g, const float* __restrict__ be,
        const float* __restrict__ m, const float* __restrict__ v,
        unsigned short* __restrict__ H, int N) {
    __shared__ short8v al[16 * 8];  // 16 rows x 8 slots (K=64)
    int tid = threadIdx.x, wv = tid >> 6, lane = tid & 63;
    int lr = lane & 15, lh = lane >> 4;
    short8v bw[2];
    {
        const float* wrow = W + (size_t)(wv * 16 + lr) * 64;
#pragma unroll
        for (int kk = 0; kk < 2; kk++) {
            float tmp[8];
            *(float4*)tmp = *(const float4*)(wrow + kk * 32 + lh * 8);
            *(float4*)(tmp + 4) = *(const float4*)(wrow + kk * 32 + lh * 8 + 4);
            bw[kk] = pack8(tmp);
        }
    }
    int col = wv * 16 + lr;
    float bias = b[col];
    float sc = g[col] * rsqrtf(v[col] + BN_EPS);
    float cc = be[col] - m[col] * sc;
    int rr = tid >> 3, ss = tid & 7;  // staging: threads 0..127
    for (int nb = blockIdx.x * 16; nb < N; nb += gridDim.x * 16) {
        if (tid < 128) {
            const short8v* tg = (const short8v*)(T + (size_t)(nb + rr) * 64);
            al[rr * 8 + (ss ^ (rr & 7))] = tg[ss];
        }
        __syncthreads();
        f32x4 acc = {0.f, 0.f, 0.f, 0.f};
#pragma unroll
        for (int kk = 0; kk < 2; kk++) {
            short8v a = al[lr * 8 + ((kk * 4 + lh) ^ (lr & 7))];
            acc = __builtin_amdgcn_mfma_f32_16x16x32_bf16(a, bw[kk], acc, 0, 0, 0);
        }
        unsigned short* hb = H + (size_t)nb * 64 + col;
#pragma unroll
        for (int ri = 0; ri < 4; ri++) {
            float o = fmaxf((acc[ri] + bias) * sc + cc, 0.f);
            hb[(size_t)(lh * 4 + ri) * 64] = f2bf(o);
        }
        __syncthreads();
    }
}

// Y(bf16) = relu(bn(T@W1^T + b1)) @ W2^T   (T bf16, both K=64; no out bias)
__global__ __launch_bounds__(256) void mlp2_mfma(const unsigned short* __restrict__ T,
        const float* __restrict__ W1, const float* __restrict__ b1,
        const float* __restrict__ g, const float* __restrict__ be,
        const float* __restrict__ m, const float* __restrict__ v,
        const float* __restrict__ W2, unsigned short* __restrict__ Y, int N) {
    __shared__ short8v al[16 * 8];
    __shared__ short8v hl[16 * 8];
    int tid = threadIdx.x, wv = tid >> 6, lane = tid & 63;
    int lr = lane & 15, lh = lane >> 4;
    short8v bw1[2], bw2[2];
    {
        const float* w1r = W1 + (size_t)(wv * 16 + lr) * 64;
        const float* w2r = W2 + (size_t)(wv * 16 + lr) * 64;
#pragma unroll
        for (int kk = 0; kk < 2; kk++) {
            float tmp[8];
            *(float4*)tmp = *(const float4*)(w1r + kk * 32 + lh * 8);
            *(float4*)(tmp + 4) = *(const float4*)(w1r + kk * 32 + lh * 8 + 4);
            bw1[kk] = pack8(tmp);
            *(float4*)tmp = *(const float4*)(w2r + kk * 32 + lh * 8);
            *(float4*)(tmp + 4) = *(const float4*)(w2r + kk * 32 + lh * 8 + 4);
            bw2[kk] = pack8(tmp);
        }
    }
    int col = wv * 16 + lr;
    float bias = b1[col];
    float sc = g[col] * rsqrtf(v[col] + BN_EPS);
    float cc = be[col] - m[col] * sc;
    unsigned short* hu = (unsigned short*)hl;
    int rr = tid >> 3, ss = tid & 7;
    for (int nb = blockIdx.x * 16; nb < N; nb += gridDim.x * 16) {
        if (tid < 128) {
            const short8v* tg = (const short8v*)(T + (size_t)(nb + rr) * 64);
            al[rr * 8 + (ss ^ (rr & 7))] = tg[ss];
        }
        __syncthreads();
        f32x4 acc = {0.f, 0.f, 0.f, 0.f};
#pragma unroll
        for (int kk = 0; kk < 2; kk++) {
            short8v a = al[lr * 8 + ((kk * 4 + lh) ^ (lr & 7))];
            acc = __builtin_amdgcn_mfma_f32_16x16x32_bf16(a, bw1[kk], acc, 0, 0, 0);
        }
        // relu(bn(.)) -> hl (swizzled [16][64] bf16)
#pragma unroll
        for (int ri = 0; ri < 4; ri++) {
            float o = fmaxf((acc[ri] + bias) * sc + cc, 0.f);
            int row = lh * 4 + ri;
            int slot = (col >> 3) ^ (row & 7);
            hu[(row * 8 + slot) * 8 + (col & 7)] = f2bf(o);
        }
        __syncthreads();
        f32x4 acc2 = {0.f, 0.f, 0.f, 0.f};
#pragma unroll
        for (int kk = 0; kk < 2; kk++) {
            short8v a = hl[lr * 8 + ((kk * 4 + lh) ^ (lr & 7))];
            acc2 = __builtin_amdgcn_mfma_f32_16x16x32_bf16(a, bw2[kk], acc2, 0, 0, 0);
        }
        unsigned short* yb = Y + (size_t)nb * 64 + col;
#pragma unroll
        for (int ri = 0; ri < 4; ri++)
            yb[(size_t)(lh * 4 + ri) * 64] = f2bf(acc2[ri]);
        __syncthreads();
    }
}

// ---------------- gather: T[i](bf16) = relu(Y[i] + bias + sum_{e} Y[src[e]]) ----------------
__global__ __launch_bounds__(256) void gather_kernel(const unsigned short* __restrict__ Y,
                                                     const int* __restrict__ row_ptr,
                                                     const int* __restrict__ esrc,
                                                     const float* __restrict__ bias,
                                                     unsigned short* __restrict__ T, int N) {
    int wv = threadIdx.x >> 6, lane = threadIdx.x & 63;
    int node = blockIdx.x * 4 + wv;
    if (node >= N) return;
    float acc = bf2f(Y[(size_t)node * 64 + lane]) + bias[lane];
    int e0 = row_ptr[node], e1 = row_ptr[node + 1];
    int e = e0;
    for (; e + 8 <= e1; e += 8) {
        int s0 = esrc[e], s1 = esrc[e + 1], s2 = esrc[e + 2], s3 = esrc[e + 3];
        int s4 = esrc[e + 4], s5 = esrc[e + 5], s6 = esrc[e + 6], s7 = esrc[e + 7];
        float f0 = bf2f(Y[(size_t)s0 * 64 + lane]);
        float f1 = bf2f(Y[(size_t)s1 * 64 + lane]);
        float f2 = bf2f(Y[(size_t)s2 * 64 + lane]);
        float f3 = bf2f(Y[(size_t)s3 * 64 + lane]);
        float f4 = bf2f(Y[(size_t)s4 * 64 + lane]);
        float f5 = bf2f(Y[(size_t)s5 * 64 + lane]);
        float f6 = bf2f(Y[(size_t)s6 * 64 + lane]);
        float f7 = bf2f(Y[(size_t)s7 * 64 + lane]);
        acc += ((f0 + f1) + (f2 + f3)) + ((f4 + f5) + (f6 + f7));
    }
    for (; e < e1; e++) acc += bf2f(Y[(size_t)esrc[e] * 64 + lane]);
    T[(size_t)node * 64 + lane] = f2bf(fmaxf(acc, 0.f));
}

// ---------------- mean pool per graph (batch is sorted) ----------------
__global__ __launch_bounds__(256) void pool_kernel(const unsigned short* __restrict__ H,
                                                   const int* __restrict__ batch,
                                                   float* __restrict__ out, int N) {
    __shared__ float part[4][64];
    int g = blockIdx.x;
    int tid = threadIdx.x, wv = tid >> 6, lane = tid & 63;
    int lo = 0, hi = N;
    while (lo < hi) { int mid = (lo + hi) >> 1; if (batch[mid] < g) lo = mid + 1; else hi = mid; }
    int start = lo;
    hi = N;
    while (lo < hi) { int mid = (lo + hi) >> 1; if (batch[mid] < g + 1) lo = mid + 1; else hi = mid; }
    int end = lo;
    float acc = 0.f;
    for (int i = start + wv; i < end; i += 4) acc += bf2f(H[(size_t)i * 64 + lane]);
    part[wv][lane] = acc;
    __syncthreads();
    if (tid < 64) {
        float sfin = part[0][tid] + part[1][tid] + part[2][tid] + part[3][tid];
        float cnt = (float)(end - start);
        out[(size_t)g * 64 + tid] = sfin / fmaxf(cnt, 1.f);
    }
}

extern "C" void kernel_launch(void* const* d_in, const int* in_sizes, int n_in,
                              void* d_out, int out_size, void* d_ws, size_t ws_size,
                              hipStream_t stream) {
    const float* x   = (const float*)d_in[0];
    const int*   ei  = (const int*)d_in[1];
    const int*   bat = (const int*)d_in[2];
    const float* W1a = (const float*)d_in[3];
    const float* b1a = (const float*)d_in[4];
    const float* W1b = (const float*)d_in[5];
    const float* b1b = (const float*)d_in[6];
    const float* g1  = (const float*)d_in[7];
    const float* be1 = (const float*)d_in[8];
    const float* m1  = (const float*)d_in[9];
    const float* v1  = (const float*)d_in[10];
    const float* W2a = (const float*)d_in[11];
    const float* b2a = (const float*)d_in[12];
    const float* W2b = (const float*)d_in[13];
    const float* b2b = (const float*)d_in[14];
    const float* g2  = (const float*)d_in[15];
    const float* be2 = (const float*)d_in[16];
    const float* m2  = (const float*)d_in[17];
    const float* v2  = (const float*)d_in[18];
    float* out = (float*)d_out;

    int N = in_sizes[0] / 128;
    int E = in_sizes[1] / 2;
    int G = out_size / 64;
    int nbuck = (N + 255) >> 8;

    // workspace layout (bf16 feature buffers)
    char* ws = (char*)d_ws;
    int* row_ptr = (int*)ws;                              // N+1 (padded)
    int* bcnt = row_ptr + ((N + 1 + 3) & ~3);             // MAXB
    int* boff = bcnt + MAXB;                              // MAXB+1
    int* bpos = boff + MAXB + 4;                          // MAXB
    int* esrc = bpos + MAXB;                              // E
    unsigned short* bufA = (unsigned short*)(esrc + E);   // N*64 bf16
    unsigned short* bufB = bufA + (size_t)N * 64;         // N*64 bf16
    int* binned = (int*)bufB;                             // aliases bufB (dead until gather#1)

    // CSR build
    hipMemsetAsync(bcnt, 0, MAXB * sizeof(int), stream);
    bin_count<<<512, 256, 0, stream>>>(ei, E, bcnt, nbuck);
    scan_small<<<1, 512, 0, stream>>>(bcnt, boff, bpos, row_ptr + N, nbuck, E);
    bin_scatter<<<(E + CHUNK - 1) / CHUNK, 256, 0, stream>>>(ei, E, bpos, binned, nbuck);
    bucket_csr<<<nbuck, 256, 0, stream>>>(binned, boff, row_ptr, esrc, N);

    // layer 1
    linear_mfma<<<2048, 256, 0, stream>>>(x, W1a, bufA, N);
    gather_kernel<<<(N + 3) / 4, 256, 0, stream>>>(bufA, row_ptr, esrc, b1a, bufB, N);
    mlp2_mfma<<<2048, 256, 0, stream>>>(bufB, W1b, b1b, g1, be1, m1, v1, W2a, bufA, N);

    // layer 2
    gather_kernel<<<(N + 3) / 4, 256, 0, stream>>>(bufA, row_ptr, esrc, b2a, bufB, N);
    mlp1_mfma<<<2048, 256, 0, stream>>>(bufB, W2b, b2b, g2, be2, m2, v2, bufA, N);

    // mean pool
    pool_kernel<<<G, 256, 0, stream>>>(bufA, bat, out, N);
}

// Round 2
// 341.446 us; speedup vs baseline: 1.3296x; 1.1107x over previous
//
#include <hip/hip_runtime.h>

#define BN_EPS 1e-5f
#define CHUNK 4096
#define MAXB 512  // max buckets (N up to 131072 with 256 nodes/bucket)

typedef __attribute__((ext_vector_type(8))) short short8v;  // 8 bf16 = 4 VGPRs
typedef __attribute__((ext_vector_type(4))) float f32x4;

// bf16 helpers (RNE pack, cheap unpack)
__device__ __forceinline__ unsigned short f2bf(float f) {
    unsigned int u = __float_as_uint(f);
    u += 0x7FFF + ((u >> 16) & 1);
    return (unsigned short)(u >> 16);
}
__device__ __forceinline__ float bf2f(unsigned short h) {
    return __uint_as_float((unsigned int)h << 16);
}

__device__ __forceinline__ short8v pack8(const float* f) {
    short8v r;
#pragma unroll
    for (int i = 0; i < 8; i++) r[i] = (short)f2bf(f[i]);
    return r;
}

// ---------------- CSR build: bucketed, no global random scatter ----------------

__global__ __launch_bounds__(256) void bin_count(const int* __restrict__ ei, int E,
                                                 int* __restrict__ bcnt, int nbuck) {
    __shared__ int h[MAXB];
    for (int i = threadIdx.x; i < nbuck; i += 256) h[i] = 0;
    __syncthreads();
    int i = blockIdx.x * 256 + threadIdx.x, stride = gridDim.x * 256;
    for (int e = i; e < E; e += stride) {
        int d = ei[E + e];
        atomicAdd(&h[d >> 8], 1);
    }
    __syncthreads();
    for (int b = threadIdx.x; b < nbuck; b += 256)
        if (h[b]) atomicAdd(&bcnt[b], h[b]);
}

__global__ __launch_bounds__(512) void scan_small(const int* __restrict__ bcnt,
                                                  int* __restrict__ boff,
                                                  int* __restrict__ bpos,
                                                  int* __restrict__ row_ptr_end,
                                                  int nbuck, int E) {
    __shared__ int wsum[8];
    int tid = threadIdx.x, lane = tid & 63, wv = tid >> 6;
    int val = (tid < nbuck) ? bcnt[tid] : 0;
    int s = val;
#pragma unroll
    for (int off = 1; off < 64; off <<= 1) {
        int t = __shfl_up(s, off, 64);
        if (lane >= off) s += t;
    }
    if (lane == 63) wsum[wv] = s;
    __syncthreads();
    if (wv == 0) {
        int t = (lane < 8) ? wsum[lane] : 0;
#pragma unroll
        for (int off = 1; off < 8; off <<= 1) {
            int u = __shfl_up(t, off, 64);
            if (lane >= off) t += u;
        }
        if (lane < 8) wsum[lane] = t;
    }
    __syncthreads();
    int excl = ((wv == 0) ? 0 : wsum[wv - 1]) + s - val;
    if (tid < nbuck) { boff[tid] = excl; bpos[tid] = excl; }
    if (tid == 0) { boff[nbuck] = E; *row_ptr_end = E; }
}

__global__ __launch_bounds__(256) void bin_scatter(const int* __restrict__ ei, int E,
                                                   int* __restrict__ bpos,
                                                   int* __restrict__ binned, int nbuck) {
    __shared__ int h[MAXB];
    __shared__ int res[MAXB];
    int base = blockIdx.x * CHUNK;
    int cnt = min(CHUNK, E - base);
    int tid = threadIdx.x;
    for (int b = tid; b < nbuck; b += 256) h[b] = 0;
    __syncthreads();
    for (int k = tid; k < cnt; k += 256) {
        int d = ei[E + base + k];
        atomicAdd(&h[d >> 8], 1);
    }
    __syncthreads();
    for (int b = tid; b < nbuck; b += 256) {
        int c = h[b];
        res[b] = c ? atomicAdd(&bpos[b], c) : 0;
        h[b] = 0;  // reuse as rank counter
    }
    __syncthreads();
    for (int k = tid; k < cnt; k += 256) {
        int srcv = ei[base + k];
        int d = ei[E + base + k];
        int b = d >> 8;
        int r = atomicAdd(&h[b], 1);
        binned[res[b] + r] = ((d & 255) << 17) | srcv;  // src < 2^17
    }
}

__global__ __launch_bounds__(256) void bucket_csr(const int* __restrict__ binned,
                                                  const int* __restrict__ boff,
                                                  int* __restrict__ row_ptr,
                                                  int* __restrict__ esrc, int N) {
    __shared__ int ncnt[256];
    __shared__ int npos[256];
    __shared__ int wsum[4];
    int b = blockIdx.x, tid = threadIdx.x, lane = tid & 63, wv = tid >> 6;
    int lo = boff[b], hi = boff[b + 1];
    int base_node = b << 8;
    ncnt[tid] = 0;
    __syncthreads();
    for (int i = lo + tid; i < hi; i += 256)
        atomicAdd(&ncnt[binned[i] >> 17], 1);
    __syncthreads();
    int c = ncnt[tid];
    int s = c;
#pragma unroll
    for (int off = 1; off < 64; off <<= 1) {
        int t = __shfl_up(s, off, 64);
        if (lane >= off) s += t;
    }
    if (lane == 63) wsum[wv] = s;
    __syncthreads();
    int woff = 0;
#pragma unroll
    for (int i = 0; i < 4; i++) woff += (i < wv) ? wsum[i] : 0;
    int abspos = lo + woff + (s - c);
    if (base_node + tid < N) row_ptr[base_node + tid] = abspos;
    npos[tid] = abspos;
    __syncthreads();
    for (int i = lo + tid; i < hi; i += 256) {
        int val = binned[i];
        int r = atomicAdd(&npos[val >> 17], 1);
        esrc[r] = val & 0x1FFFF;
    }
}

// ---------------- MFMA dense kernels ----------------
// Layout facts (gfx950 mfma_f32_16x16x32_bf16):
//   A frag: lane holds A[lane&15][(lane>>4)*8 + j], j=0..7 (short8v)
//   B frag: lane holds B[(lane>>4)*8 + j][lane&15]  (here = W[col][k] rows)
//   D frag: lane&15 = col, row = (lane>>4)*4 + reg
// LDS A-tile: 16 rows x (K/8) 16B slots, slot XOR-swizzled by row -> 2-way (free)

// Y[n][64](bf16) = X[n][128](f32) @ W[64][128]^T   (no bias; added in gather)
__global__ __launch_bounds__(256) void linear_mfma(const float* __restrict__ X,
                                                   const float* __restrict__ W,
                                                   unsigned short* __restrict__ Y, int N) {
    __shared__ short8v al[16 * 16];  // 16 rows x 16 slots (K=128)
    int tid = threadIdx.x, wv = tid >> 6, lane = tid & 63;
    int lr = lane & 15, lh = lane >> 4;
    // preload B frags: wave wv owns output cols [wv*16, wv*16+16)
    short8v bw[4];
    {
        const float* wrow = W + (size_t)(wv * 16 + lr) * 128;
#pragma unroll
        for (int kk = 0; kk < 4; kk++) {
            float tmp[8];
            *(float4*)tmp = *(const float4*)(wrow + kk * 32 + lh * 8);
            *(float4*)(tmp + 4) = *(const float4*)(wrow + kk * 32 + lh * 8 + 4);
            bw[kk] = pack8(tmp);
        }
    }
    int r = tid >> 4, s = tid & 15;  // staging: thread -> (row, slot)
    for (int nb = blockIdx.x * 16; nb < N; nb += gridDim.x * 16) {
        const float* xg = X + (size_t)(nb + r) * 128 + s * 8;
        float tmp[8];
        *(float4*)tmp = *(const float4*)xg;
        *(float4*)(tmp + 4) = *(const float4*)(xg + 4);
        al[r * 16 + (s ^ r)] = pack8(tmp);
        __syncthreads();
        f32x4 acc = {0.f, 0.f, 0.f, 0.f};
#pragma unroll
        for (int kk = 0; kk < 4; kk++) {
            short8v a = al[lr * 16 + ((kk * 4 + lh) ^ lr)];
            acc = __builtin_amdgcn_mfma_f32_16x16x32_bf16(a, bw[kk], acc, 0, 0, 0);
        }
        unsigned short* yb = Y + (size_t)nb * 64 + wv * 16 + lr;
#pragma unroll
        for (int ri = 0; ri < 4; ri++)
            yb[(size_t)(lh * 4 + ri) * 64] = f2bf(acc[ri]);
        __syncthreads();
    }
}

// H(bf16) = relu(bn(T@W^T + b))   (T bf16, K=64)
__global__ __launch_bounds__(256) void mlp1_mfma(const unsigned short* __restrict__ T,
        const float* __restrict__ W, const float* __restrict__ b,
        const float* __restrict__ g, const float* __restrict__ be,
        const float* __restrict__ m, const float* __restrict__ v,
        unsigned short* __restrict__ H, int N) {
    __shared__ short8v al[16 * 8];  // 16 rows x 8 slots (K=64)
    int tid = threadIdx.x, wv = tid >> 6, lane = tid & 63;
    int lr = lane & 15, lh = lane >> 4;
    short8v bw[2];
    {
        const float* wrow = W + (size_t)(wv * 16 + lr) * 64;
#pragma unroll
        for (int kk = 0; kk < 2; kk++) {
            float tmp[8];
            *(float4*)tmp = *(const float4*)(wrow + kk * 32 + lh * 8);
            *(float4*)(tmp + 4) = *(const float4*)(wrow + kk * 32 + lh * 8 + 4);
            bw[kk] = pack8(tmp);
        }
    }
    int col = wv * 16 + lr;
    float bias = b[col];
    float sc = g[col] * rsqrtf(v[col] + BN_EPS);
    float cc = be[col] - m[col] * sc;
    int rr = tid >> 3, ss = tid & 7;  // staging: threads 0..127
    for (int nb = blockIdx.x * 16; nb < N; nb += gridDim.x * 16) {
        if (tid < 128) {
            const short8v* tg = (const short8v*)(T + (size_t)(nb + rr) * 64);
            al[rr * 8 + (ss ^ (rr & 7))] = tg[ss];
        }
        __syncthreads();
        f32x4 acc = {0.f, 0.f, 0.f, 0.f};
#pragma unroll
        for (int kk = 0; kk < 2; kk++) {
            short8v a = al[lr * 8 + ((kk * 4 + lh) ^ (lr & 7))];
            acc = __builtin_amdgcn_mfma_f32_16x16x32_bf16(a, bw[kk], acc, 0, 0, 0);
        }
        unsigned short* hb = H + (size_t)nb * 64 + col;
#pragma unroll
        for (int ri = 0; ri < 4; ri++) {
            float o = fmaxf((acc[ri] + bias) * sc + cc, 0.f);
            hb[(size_t)(lh * 4 + ri) * 64] = f2bf(o);
        }
        __syncthreads();
    }
}

// Y(bf16) = relu(bn(T@W1^T + b1)) @ W2^T   (T bf16, both K=64; no out bias)
__global__ __launch_bounds__(256) void mlp2_mfma(const unsigned short* __restrict__ T,
        const float* __restrict__ W1, const float* __restrict__ b1,
        const float* __restrict__ g, const float* __restrict__ be,
        const float* __restrict__ m, const float* __restrict__ v,
        const float* __restrict__ W2, unsigned short* __restrict__ Y, int N) {
    __shared__ short8v al[16 * 8];
    __shared__ short8v hl[16 * 8];
    int tid = threadIdx.x, wv = tid >> 6, lane = tid & 63;
    int lr = lane & 15, lh = lane >> 4;
    short8v bw1[2], bw2[2];
    {
        const float* w1r = W1 + (size_t)(wv * 16 + lr) * 64;
        const float* w2r = W2 + (size_t)(wv * 16 + lr) * 64;
#pragma unroll
        for (int kk = 0; kk < 2; kk++) {
            float tmp[8];
            *(float4*)tmp = *(const float4*)(w1r + kk * 32 + lh * 8);
            *(float4*)(tmp + 4) = *(const float4*)(w1r + kk * 32 + lh * 8 + 4);
            bw1[kk] = pack8(tmp);
            *(float4*)tmp = *(const float4*)(w2r + kk * 32 + lh * 8);
            *(float4*)(tmp + 4) = *(const float4*)(w2r + kk * 32 + lh * 8 + 4);
            bw2[kk] = pack8(tmp);
        }
    }
    int col = wv * 16 + lr;
    float bias = b1[col];
    float sc = g[col] * rsqrtf(v[col] + BN_EPS);
    float cc = be[col] - m[col] * sc;
    unsigned short* hu = (unsigned short*)hl;
    int rr = tid >> 3, ss = tid & 7;
    for (int nb = blockIdx.x * 16; nb < N; nb += gridDim.x * 16) {
        if (tid < 128) {
            const short8v* tg = (const short8v*)(T + (size_t)(nb + rr) * 64);
            al[rr * 8 + (ss ^ (rr & 7))] = tg[ss];
        }
        __syncthreads();
        f32x4 acc = {0.f, 0.f, 0.f, 0.f};
#pragma unroll
        for (int kk = 0; kk < 2; kk++) {
            short8v a = al[lr * 8 + ((kk * 4 + lh) ^ (lr & 7))];
            acc = __builtin_amdgcn_mfma_f32_16x16x32_bf16(a, bw1[kk], acc, 0, 0, 0);
        }
        // relu(bn(.)) -> hl (swizzled [16][64] bf16)
#pragma unroll
        for (int ri = 0; ri < 4; ri++) {
            float o = fmaxf((acc[ri] + bias) * sc + cc, 0.f);
            int row = lh * 4 + ri;
            int slot = (col >> 3) ^ (row & 7);
            hu[(row * 8 + slot) * 8 + (col & 7)] = f2bf(o);
        }
        __syncthreads();
        f32x4 acc2 = {0.f, 0.f, 0.f, 0.f};
#pragma unroll
        for (int kk = 0; kk < 2; kk++) {
            short8v a = hl[lr * 8 + ((kk * 4 + lh) ^ (lr & 7))];
            acc2 = __builtin_amdgcn_mfma_f32_16x16x32_bf16(a, bw2[kk], acc2, 0, 0, 0);
        }
        unsigned short* yb = Y + (size_t)nb * 64 + col;
#pragma unroll
        for (int ri = 0; ri < 4; ri++)
            yb[(size_t)(lh * 4 + ri) * 64] = f2bf(acc2[ri]);
        __syncthreads();
    }
}

// ---------------- gather: T[i](bf16) = relu(Y[i] + bias + sum_{e} Y[src[e]]) ----------------
// v2: 2 nodes per wave (16 row-loads in flight), masked 8-wide tail (no serial chain).
// Clamped duplicate loads hit L1 -> free; mask via wave-uniform cndmask.
__global__ __launch_bounds__(256) void gather_kernel(const unsigned short* __restrict__ Y,
                                                     const int* __restrict__ row_ptr,
                                                     const int* __restrict__ esrc,
                                                     const float* __restrict__ bias,
                                                     unsigned short* __restrict__ T, int N) {
    int wv = threadIdx.x >> 6, lane = threadIdx.x & 63;
    int n0 = blockIdx.x * 8 + wv * 2;
    if (n0 >= N) return;
    int n1 = n0 + 1;
    bool has1 = n1 < N;
    int e0a = row_ptr[n0];
    int e1a = row_ptr[n0 + 1];
    int e1b = has1 ? row_ptr[n1 + 1] : e1a;
    float bv = bias[lane];
    float acca = bf2f(Y[(size_t)n0 * 64 + lane]) + bv;
    float accb = has1 ? (bf2f(Y[(size_t)n1 * 64 + lane]) + bv) : 0.f;
    int ea = e0a, eb = e1a;
    int la = max(e1a - 1, 0);
    int lb = max(e1b - 1, 0);
    // joint loop: both streams active, 16 loads in flight
    while (ea < e1a && eb < e1b) {
        int sa[8], sb[8];
#pragma unroll
        for (int i = 0; i < 8; i++) {
            int ia = ea + i;
            int ib = eb + i;
            sa[i] = esrc[ia < e1a ? ia : la];
            sb[i] = esrc[ib < e1b ? ib : lb];
        }
        float fa[8], fb[8];
#pragma unroll
        for (int i = 0; i < 8; i++) fa[i] = bf2f(Y[(size_t)sa[i] * 64 + lane]);
#pragma unroll
        for (int i = 0; i < 8; i++) fb[i] = bf2f(Y[(size_t)sb[i] * 64 + lane]);
        float suma = 0.f, sumb = 0.f;
#pragma unroll
        for (int i = 0; i < 8; i++) {
            suma += (ea + i < e1a) ? fa[i] : 0.f;
            sumb += (eb + i < e1b) ? fb[i] : 0.f;
        }
        acca += suma;
        accb += sumb;
        ea += 8;
        eb += 8;
    }
    // leftover stream a
    while (ea < e1a) {
        int sa[8];
#pragma unroll
        for (int i = 0; i < 8; i++) { int ia = ea + i; sa[i] = esrc[ia < e1a ? ia : la]; }
        float fa[8];
#pragma unroll
        for (int i = 0; i < 8; i++) fa[i] = bf2f(Y[(size_t)sa[i] * 64 + lane]);
        float suma = 0.f;
#pragma unroll
        for (int i = 0; i < 8; i++) suma += (ea + i < e1a) ? fa[i] : 0.f;
        acca += suma;
        ea += 8;
    }
    // leftover stream b
    while (eb < e1b) {
        int sb[8];
#pragma unroll
        for (int i = 0; i < 8; i++) { int ib = eb + i; sb[i] = esrc[ib < e1b ? ib : lb]; }
        float fb[8];
#pragma unroll
        for (int i = 0; i < 8; i++) fb[i] = bf2f(Y[(size_t)sb[i] * 64 + lane]);
        float sumb = 0.f;
#pragma unroll
        for (int i = 0; i < 8; i++) sumb += (eb + i < e1b) ? fb[i] : 0.f;
        accb += sumb;
        eb += 8;
    }
    T[(size_t)n0 * 64 + lane] = f2bf(fmaxf(acca, 0.f));
    if (has1) T[(size_t)n1 * 64 + lane] = f2bf(fmaxf(accb, 0.f));
}

// ---------------- mean pool per graph (batch is sorted) ----------------
__global__ __launch_bounds__(256) void pool_kernel(const unsigned short* __restrict__ H,
                                                   const int* __restrict__ batch,
                                                   float* __restrict__ out, int N) {
    __shared__ float part[4][64];
    int g = blockIdx.x;
    int tid = threadIdx.x, wv = tid >> 6, lane = tid & 63;
    int lo = 0, hi = N;
    while (lo < hi) { int mid = (lo + hi) >> 1; if (batch[mid] < g) lo = mid + 1; else hi = mid; }
    int start = lo;
    hi = N;
    while (lo < hi) { int mid = (lo + hi) >> 1; if (batch[mid] < g + 1) lo = mid + 1; else hi = mid; }
    int end = lo;
    float acc = 0.f;
    for (int i = start + wv; i < end; i += 4) acc += bf2f(H[(size_t)i * 64 + lane]);
    part[wv][lane] = acc;
    __syncthreads();
    if (tid < 64) {
        float sfin = part[0][tid] + part[1][tid] + part[2][tid] + part[3][tid];
        float cnt = (float)(end - start);
        out[(size_t)g * 64 + tid] = sfin / fmaxf(cnt, 1.f);
    }
}

extern "C" void kernel_launch(void* const* d_in, const int* in_sizes, int n_in,
                              void* d_out, int out_size, void* d_ws, size_t ws_size,
                              hipStream_t stream) {
    const float* x   = (const float*)d_in[0];
    const int*   ei  = (const int*)d_in[1];
    const int*   bat = (const int*)d_in[2];
    const float* W1a = (const float*)d_in[3];
    const float* b1a = (const float*)d_in[4];
    const float* W1b = (const float*)d_in[5];
    const float* b1b = (const float*)d_in[6];
    const float* g1  = (const float*)d_in[7];
    const float* be1 = (const float*)d_in[8];
    const float* m1  = (const float*)d_in[9];
    const float* v1  = (const float*)d_in[10];
    const float* W2a = (const float*)d_in[11];
    const float* b2a = (const float*)d_in[12];
    const float* W2b = (const float*)d_in[13];
    const float* b2b = (const float*)d_in[14];
    const float* g2  = (const float*)d_in[15];
    const float* be2 = (const float*)d_in[16];
    const float* m2  = (const float*)d_in[17];
    const float* v2  = (const float*)d_in[18];
    float* out = (float*)d_out;

    int N = in_sizes[0] / 128;
    int E = in_sizes[1] / 2;
    int G = out_size / 64;
    int nbuck = (N + 255) >> 8;

    // workspace layout (bf16 feature buffers)
    char* ws = (char*)d_ws;
    int* row_ptr = (int*)ws;                              // N+1 (padded)
    int* bcnt = row_ptr + ((N + 1 + 3) & ~3);             // MAXB
    int* boff = bcnt + MAXB;                              // MAXB+1
    int* bpos = boff + MAXB + 4;                          // MAXB
    int* esrc = bpos + MAXB;                              // E
    unsigned short* bufA = (unsigned short*)(esrc + E);   // N*64 bf16
    unsigned short* bufB = bufA + (size_t)N * 64;         // N*64 bf16
    int* binned = (int*)bufB;                             // aliases bufB (dead until gather#1)

    // CSR build
    hipMemsetAsync(bcnt, 0, MAXB * sizeof(int), stream);
    bin_count<<<512, 256, 0, stream>>>(ei, E, bcnt, nbuck);
    scan_small<<<1, 512, 0, stream>>>(bcnt, boff, bpos, row_ptr + N, nbuck, E);
    bin_scatter<<<(E + CHUNK - 1) / CHUNK, 256, 0, stream>>>(ei, E, bpos, binned, nbuck);
    bucket_csr<<<nbuck, 256, 0, stream>>>(binned, boff, row_ptr, esrc, N);

    // layer 1
    linear_mfma<<<2048, 256, 0, stream>>>(x, W1a, bufA, N);
    gather_kernel<<<(N + 7) / 8, 256, 0, stream>>>(bufA, row_ptr, esrc, b1a, bufB, N);
    mlp2_mfma<<<2048, 256, 0, stream>>>(bufB, W1b, b1b, g1, be1, m1, v1, W2a, bufA, N);

    // layer 2
    gather_kernel<<<(N + 7) / 8, 256, 0, stream>>>(bufA, row_ptr, esrc, b2a, bufB, N);
    mlp1_mfma<<<2048, 256, 0, stream>>>(bufB, W2b, b2b, g2, be2, m2, v2, bufA, N);

    // mean pool
    pool_kernel<<<G, 256, 0, stream>>>(bufA, bat, out, N);
}